// Round 8
// baseline (70.253 us; speedup 1.0000x reference)
//
#include <hip/hip_runtime.h>
#include <hip/hip_bf16.h>

// B=2, M=256, N=256, K=8, P=Q=Pp=Qp=512, D=Dp=64, R=128, TEMP=8
#define LOG2E_OVER_T 0.18033688011112042f  // log2(e)/8

typedef __attribute__((ext_vector_type(8))) short short8;
typedef __attribute__((ext_vector_type(4))) float f32x4;
typedef unsigned short ushort_t;
typedef unsigned long long ull_t;

#define MFMA16(a, b, c) __builtin_amdgcn_mfma_f32_16x16x32_bf16(a, b, c, 0, 0, 0)

__device__ __forceinline__ ushort_t f2bf(float f) {
    union { float f; unsigned u; } v; v.f = f;
    unsigned r = (v.u + 0x7fffu + ((v.u >> 16) & 1u)) >> 16;
    return (ushort_t)r;
}

// split 8 fp32 -> bf16 hi (truncate) + bf16 lo (residual, truncate).
__device__ __forceinline__ void split8(const float4 a, const float4 b,
                                       short8& hi, short8& lo)
{
    union { float f[8]; unsigned u[8]; } Z;
    Z.f[0] = a.x; Z.f[1] = a.y; Z.f[2] = a.z; Z.f[3] = a.w;
    Z.f[4] = b.x; Z.f[5] = b.y; Z.f[6] = b.z; Z.f[7] = b.w;
    union { unsigned u[4]; short8 s; } H, L;
    #pragma unroll
    for (int i = 0; i < 4; i++) {
        const unsigned u0 = Z.u[2 * i], u1 = Z.u[2 * i + 1];
        H.u[i] = __builtin_amdgcn_perm(u1, u0, 0x07060302u);  // [u0.hi16, u1.hi16]
        union { unsigned u; float f; } h0, h1;
        h0.u = u0 & 0xffff0000u; h1.u = u1 & 0xffff0000u;
        union { float f; unsigned u; } l0, l1;
        l0.f = Z.f[2 * i] - h0.f; l1.f = Z.f[2 * i + 1] - h1.f;
        L.u[i] = __builtin_amdgcn_perm(l1.u, l0.u, 0x07060302u);
    }
    hi = H.s; lo = L.s;
}

// ---------------------------------------------------------------------------
// MFMA core: C[64x64] = A[64xK] * Bt[64xK]^T, bf16 in, fp32 acc. (4 waves)
// ---------------------------------------------------------------------------
__device__ __forceinline__ void mfma_core64(
    const ushort_t* __restrict__ Ag, int lda,
    const ushort_t* __restrict__ Btg, int ldb,
    int ksteps, f32x4 acc[2][2])
{
    __shared__ __align__(16) ushort_t As[64 * 40];
    __shared__ __align__(16) ushort_t Bs[64 * 40];
    const int t = threadIdx.x;
    const int srow = t >> 2, skc = (t & 3) * 8;
    const int lane = t & 63, w = t >> 6;
    const int wr = w >> 1, wc = w & 1;
    const int fr = lane & 15, kg = lane >> 4;
    const int aoff = (wr * 32 + fr) * 40 + kg * 8;
    const int boff = (wc * 32 + fr) * 40 + kg * 8;
    const long arow = (long)srow * lda + skc;
    const long brow = (long)srow * ldb + skc;

    short8 ra = *(const short8*)(Ag + arow);
    short8 rb = *(const short8*)(Btg + brow);
    for (int kt = 0; kt < ksteps; kt++) {
        __syncthreads();
        *(short8*)&As[srow * 40 + skc] = ra;
        *(short8*)&Bs[srow * 40 + skc] = rb;
        __syncthreads();
        if (kt + 1 < ksteps) {
            ra = *(const short8*)(Ag + arow + (kt + 1) * 32);
            rb = *(const short8*)(Btg + brow + (kt + 1) * 32);
        }
        short8 a0 = *(const short8*)&As[aoff];
        short8 a1 = *(const short8*)&As[aoff + 16 * 40];
        short8 b0 = *(const short8*)&Bs[boff];
        short8 b1 = *(const short8*)&Bs[boff + 16 * 40];
        acc[0][0] = MFMA16(a0, b0, acc[0][0]);
        acc[0][1] = MFMA16(a0, b1, acc[0][1]);
        acc[1][0] = MFMA16(a1, b0, acc[1][0]);
        acc[1][1] = MFMA16(a1, b1, acc[1][1]);
    }
}

__device__ __forceinline__ void zero_acc(f32x4 acc[2][2]) {
    const f32x4 z4 = {0.f, 0.f, 0.f, 0.f};
    acc[0][0] = z4; acc[0][1] = z4; acc[1][0] = z4; acc[1][1] = z4;
}

// ---------------------------------------------------------------------------
// convert: fp32 -> bf16 casts + layout permutes; also zeroes ssum.
// ---------------------------------------------------------------------------
__global__ __launch_bounds__(256)
void convert_kernel(const float* __restrict__ x_k, const float* __restrict__ y_q,
                    const float* __restrict__ Lam_x, const float* __restrict__ Theta_x,
                    const float* __restrict__ Lam_y, const float* __restrict__ Lam_zy,
                    const float* __restrict__ Lam_zx, const float* __restrict__ Theta_y,
                    ushort_t* __restrict__ xkb, ushort_t* __restrict__ yqb,
                    ushort_t* __restrict__ WxTb, ushort_t* __restrict__ WyTb,
                    ushort_t* __restrict__ Zyb, ushort_t* __restrict__ Zxb,
                    ushort_t* __restrict__ TyTb, float* __restrict__ ssum)
{
    int i = blockIdx.x * 256 + threadIdx.x;
    if (i < 262144) { xkb[i] = f2bf(x_k[i]); return; }
    i -= 262144;
    if (i < 262144) { yqb[i] = f2bf(y_q[i]); return; }
    i -= 262144;
    if (i < 524288) {  // WxTb[k][dc][p] = (dc<64 ? Lam_x : Theta_x)[k][p][dc%64]
        const int k = i >> 16, rem = i & 65535, dc = rem >> 9, p = i & 511;
        const float v = (dc < 64) ? Lam_x[((long)k * 512 + p) * 64 + dc]
                                  : Theta_x[((long)k * 512 + p) * 64 + dc - 64];
        WxTb[i] = f2bf(v); return;
    }
    i -= 524288;
    if (i < 262144) {  // WyTb[k][d][p] = Lam_y[k][p][d]
        const int k = i >> 15, d = (i >> 9) & 63, p = i & 511;
        WyTb[i] = f2bf(Lam_y[((long)k * 512 + p) * 64 + d]); return;
    }
    i -= 262144;
    if (i < 65536) { Zyb[i] = f2bf(Lam_zy[i]); return; }
    i -= 65536;
    if (i < 65536) { Zxb[i] = f2bf(Lam_zx[i]); return; }
    i -= 65536;
    if (i < 262144) {  // TyTb[q][k*64+d] = Theta_y[k][q][d]
        const int q = i >> 9, kd = i & 511, k = kd >> 6, d = kd & 63;
        TyTb[i] = f2bf(Theta_y[((long)k * 512 + q) * 64 + d]); return;
    }
    i -= 262144;
    ssum[i] = 0.f;  // 4096 entries
}

// ---------------------------------------------------------------------------
// proj: side0: [b,m] x WxT -> xtb (bf16 [bk][m][64]) + xvT (bf16 [bk][64][m])
//       side1: [b,n] x WyT -> ytb (bf16 [bk][n][64])
// ---------------------------------------------------------------------------
__global__ __launch_bounds__(256)
void proj_kernel(const ushort_t* __restrict__ xkb, const ushort_t* __restrict__ yqb,
                 const ushort_t* __restrict__ WxTb, const ushort_t* __restrict__ WyTb,
                 ushort_t* __restrict__ xtb, ushort_t* __restrict__ ytb,
                 ushort_t* __restrict__ xvTb)
{
    const int side = blockIdx.z;
    const int bx = blockIdx.x, by = blockIdx.y;
    if (side == 1 && bx >= 8) return;
    f32x4 acc[2][2]; zero_acc(acc);
    const int t = threadIdx.x, lane = t & 63, w = t >> 6;
    const int wr = w >> 1, wc = w & 1, fr = lane & 15, kg = lane >> 4;

    if (side == 0) {
        mfma_core64(xkb + (long)(by * 64) * 512, 512,
                    WxTb + (long)(bx * 64) * 512, 512, 16, acc);
        const int k = bx >> 1, isxv = bx & 1;
        #pragma unroll
        for (int mi = 0; mi < 2; mi++)
        #pragma unroll
        for (int ni = 0; ni < 2; ni++) {
            const int grow0 = by * 64 + wr * 32 + mi * 16 + kg * 4;
            const int b = grow0 >> 8, m0 = grow0 & 255;
            const int d = wc * 32 + ni * 16 + fr;
            if (!isxv) {
                #pragma unroll
                for (int j = 0; j < 4; j++)
                    xtb[(((long)(b * 8 + k)) * 256 + m0 + j) * 64 + d] = f2bf(acc[mi][ni][j]);
            } else {
                ull_t pk = (ull_t)f2bf(acc[mi][ni][0])
                         | ((ull_t)f2bf(acc[mi][ni][1]) << 16)
                         | ((ull_t)f2bf(acc[mi][ni][2]) << 32)
                         | ((ull_t)f2bf(acc[mi][ni][3]) << 48);
                *(ull_t*)&xvTb[(((long)(b * 8 + k)) * 64 + d) * 256 + m0] = pk;
            }
        }
    } else {
        mfma_core64(yqb + (long)(by * 64) * 512, 512,
                    WyTb + (long)(bx * 64) * 512, 512, 16, acc);
        const int k = bx;
        #pragma unroll
        for (int mi = 0; mi < 2; mi++)
        #pragma unroll
        for (int ni = 0; ni < 2; ni++)
        #pragma unroll
        for (int j = 0; j < 4; j++) {
            const int grow = by * 64 + wr * 32 + mi * 16 + kg * 4 + j;
            const int b = grow >> 8, n = grow & 255;
            const int d = wc * 32 + ni * 16 + fr;
            ytb[(((long)(b * 8 + k)) * 256 + n) * 64 + d] = f2bf(acc[mi][ni][j]);
        }
    }
}

// ---------------------------------------------------------------------------
// step2: bz<256:  wzyb[b][m][k][128] = bf16(xt @ Lam_zy^T), wzxb likewise.
//        bz>=256: t1[bk][n][m] = fp32(yt @ xt^T)  (xt.yt scores, transposed)
// ---------------------------------------------------------------------------
__global__ __launch_bounds__(256)
void step2_kernel(const ushort_t* __restrict__ xtb, const ushort_t* __restrict__ ytb,
                  const ushort_t* __restrict__ Zyb, const ushort_t* __restrict__ Zxb,
                  ushort_t* __restrict__ wzyb, ushort_t* __restrict__ wzxb,
                  float* __restrict__ t1)
{
    const int bz = blockIdx.x;  // 512
    const int t = threadIdx.x, lane = t & 63, w = t >> 6;
    const int wr = w >> 1, wc = w & 1, fr = lane & 15, kg = lane >> 4;

    if (bz < 256) {
        const int which = bz >> 7, idx = bz & 127;
        const int bk = idx >> 3, tile = idx & 7, mt = tile >> 1, nt = tile & 1;
        const int k = bk & 7, b = bk >> 3;
        const ushort_t* Ag  = (which ? ytb : xtb) + ((long)bk * 256 + mt * 64) * 64;
        const ushort_t* Btg = (which ? Zxb : Zyb) + ((long)k * 128 + nt * 64) * 64;
        ushort_t* C = which ? wzxb : wzyb;
        f32x4 acc[2][2]; zero_acc(acc);
        mfma_core64(Ag, 64, Btg, 64, 2, acc);
        #pragma unroll
        for (int mi = 0; mi < 2; mi++)
        #pragma unroll
        for (int ni = 0; ni < 2; ni++)
        #pragma unroll
        for (int j = 0; j < 4; j++) {
            const int m_glob = mt * 64 + wr * 32 + mi * 16 + kg * 4 + j;
            const int r_glob = nt * 64 + wc * 32 + ni * 16 + fr;
            C[(((long)b * 256 + m_glob) * 8 + k) * 128 + r_glob] = f2bf(acc[mi][ni][j]);
        }
    } else {
        const int idx = bz - 256;
        const int bk = idx >> 4, tile = idx & 15, nt2 = tile >> 2, mt2 = tile & 3;
        f32x4 acc[2][2]; zero_acc(acc);
        mfma_core64(ytb + ((long)bk * 256 + nt2 * 64) * 64, 64,
                    xtb + ((long)bk * 256 + mt2 * 64) * 64, 64, 2, acc);
        #pragma unroll
        for (int mi = 0; mi < 2; mi++)
        #pragma unroll
        for (int ni = 0; ni < 2; ni++)
        #pragma unroll
        for (int j = 0; j < 4; j++) {
            const int n_glob = nt2 * 64 + wr * 32 + mi * 16 + kg * 4 + j;
            const int m_glob = mt2 * 64 + wc * 32 + ni * 16 + fr;
            t1[((long)bk * 256 + n_glob) * 256 + m_glob] = acc[mi][ni][j];
        }
    }
}

// ---------------------------------------------------------------------------
// fused_score v5: block = 4 waves (r-quarters), tile 8m x 16n. Deep batched
// loads: issue ALL loads of a batch into statically-indexed register arrays,
// sched_barrier(0) to pin them before the consume loop (prevents the compiler
// sinking loads back to uses, which serialized v3/v4 at ~1 load in flight).
//   p2 (termB, per m, batch 8): A = z[m, 16n, 32r] hi/lo, B = wzy[m][8k][32r]
//   p3 (termC, per n, 2 batches of 8): A = z[8m, n, 32r], B = wzx[n][8k][32r]
// Partials in sc[4][m][k][n]; epilogue adds t1 (xt.yt), exp -> Et + ssum.
// ---------------------------------------------------------------------------
__global__ __launch_bounds__(256, 2)
void fused_score(const float* __restrict__ z,
                 const ushort_t* __restrict__ wzyb, const ushort_t* __restrict__ wzxb,
                 const float* __restrict__ t1, ushort_t* __restrict__ Et,
                 float* __restrict__ ssum)
{
    const int nt = blockIdx.x, mt = blockIdx.y, b = blockIdx.z;
    const int nbase = nt * 16, m0 = mt * 8;
    __shared__ float sc[4][8][8][17];  // 17.4 KB [r-quarter][m][k][n+pad]

    const int tid = threadIdx.x;
    const int lane = tid & 63, w = tid >> 6;   // w = r-quarter
    const int fr = lane & 15, kg = lane >> 4;
    const int f8 = fr & 7;
    const int rh = w * 32;

    // ---- p2: termB. per m: D[row=n(kg*4+j), col=k(fr<8)]
    {
        const float* zp = z + (((long)b * 256 + m0) * 256 + nbase + fr) * 128 + rh + kg * 8;
        const ushort_t* wp = wzyb + (((long)b * 256 + m0) * 8 + f8) * 128 + rh + kg * 8;
        float4 zA[8], zB[8]; short8 wv[8];
        #pragma unroll
        for (int m = 0; m < 8; m++) {
            zA[m] = *(const float4*)(zp + m * 32768);
            zB[m] = *(const float4*)(zp + m * 32768 + 4);
            wv[m] = *(const short8*)(wp + m * 1024);
        }
        __builtin_amdgcn_sched_barrier(0);
        #pragma unroll
        for (int m = 0; m < 8; m++) {
            short8 hi, lo;
            split8(zA[m], zB[m], hi, lo);
            f32x4 acc = {0.f, 0.f, 0.f, 0.f};
            acc = MFMA16(hi, wv[m], acc);
            acc = MFMA16(lo, wv[m], acc);
            if (fr < 8) {
                #pragma unroll
                for (int j = 0; j < 4; j++)
                    sc[w][m][fr][kg * 4 + j] = acc[j];
            }
        }
    }

    // ---- p3: termC. per n: D[row=m(kg<2), col=k(fr<8)], 2 batches of 8
    {
        const float* zp = z + (((long)b * 256 + m0 + f8) * 256 + nbase) * 128 + rh + kg * 8;
        const ushort_t* wp = wzxb + (((long)b * 256 + nbase) * 8 + f8) * 128 + rh + kg * 8;
        #pragma unroll
        for (int h = 0; h < 2; h++) {
            float4 zA[8], zB[8]; short8 wv[8];
            #pragma unroll
            for (int i = 0; i < 8; i++) {
                const int n = h * 8 + i;
                zA[i] = *(const float4*)(zp + n * 128);
                zB[i] = *(const float4*)(zp + n * 128 + 4);
                wv[i] = *(const short8*)(wp + n * 1024);
            }
            __builtin_amdgcn_sched_barrier(0);
            #pragma unroll
            for (int i = 0; i < 8; i++) {
                const int n = h * 8 + i;
                short8 hi, lo;
                split8(zA[i], zB[i], hi, lo);
                f32x4 acc = {0.f, 0.f, 0.f, 0.f};
                acc = MFMA16(hi, wv[i], acc);
                acc = MFMA16(lo, wv[i], acc);
                if (fr < 8 && kg < 2) {
                    #pragma unroll
                    for (int j = 0; j < 4; j++)
                        sc[w][kg * 4 + j][fr][n] += acc[j];
                }
            }
        }
    }
    __syncthreads();

    // ---- epilogue: 128 threads, one (k,n) each: sum quarters + t1, exp
    if (tid < 128) {
        const int k = tid >> 4, n = tid & 15;
        const float* tp = t1 + (((long)b * 8 + k) * 256 + nbase + n) * 256 + m0;
        const float4 t0 = *(const float4*)(tp);
        const float4 t4 = *(const float4*)(tp + 4);
        const float tv[8] = {t0.x, t0.y, t0.z, t0.w, t4.x, t4.y, t4.z, t4.w};
        float s8 = 0.f;
        ushort_t eb[8];
        #pragma unroll
        for (int m = 0; m < 8; m++) {
            const float s = sc[0][m][k][n] + sc[1][m][k][n]
                          + sc[2][m][k][n] + sc[3][m][k][n] + tv[m];
            const float e = exp2f(s * LOG2E_OVER_T);
            eb[m] = f2bf(e);
            s8 += e;
        }
        *(short8*)(Et + (((long)b * 8 + k) * 256 + nbase + n) * 256 + m0) = *(short8*)eb;
        atomicAdd(&ssum[(b * 8 + k) * 256 + nbase + n], s8);
    }
}

// ---------------------------------------------------------------------------
// ogemm: o2b[b][n][k*64+d] = bf16( (1/ssum[bk][n]) * sum_m Et[bk][n][m]*xvT[bk][d][m] )
// ---------------------------------------------------------------------------
__global__ __launch_bounds__(256)
void ogemm_kernel(const ushort_t* __restrict__ Et, const ushort_t* __restrict__ xvTb,
                  const float* __restrict__ ssum, ushort_t* __restrict__ o2b)
{
    const int mt = blockIdx.x, bk = blockIdx.y;
    f32x4 acc[2][2]; zero_acc(acc);
    mfma_core64(Et + ((long)bk * 256 + mt * 64) * 256, 256,
                xvTb + (long)bk * 64 * 256, 256, 8, acc);
    const int t = threadIdx.x, lane = t & 63, w = t >> 6;
    const int wr = w >> 1, wc = w & 1, fr = lane & 15, kg = lane >> 4;
    const int b = bk >> 3, k = bk & 7;
    #pragma unroll
    for (int mi = 0; mi < 2; mi++)
    #pragma unroll
    for (int j = 0; j < 4; j++) {
        const int n = mt * 64 + wr * 32 + mi * 16 + kg * 4 + j;
        const float inv = 1.0f / ssum[bk * 256 + n];
        #pragma unroll
        for (int ni = 0; ni < 2; ni++) {
            const int d = wc * 32 + ni * 16 + fr;
            o2b[((long)b * 256 + n) * 512 + k * 64 + d] = f2bf(acc[mi][ni][j] * inv);
        }
    }
}

// ---------------------------------------------------------------------------
// ygemm: out[b][n][q] = sum_kd o2b[b][n][kd] * TyTb[q][kd]   (fp32 out)
// ---------------------------------------------------------------------------
__global__ __launch_bounds__(256)
void ygemm_kernel(const ushort_t* __restrict__ o2b, const ushort_t* __restrict__ TyTb,
                  float* __restrict__ out)
{
    const int qt = blockIdx.x, mt = blockIdx.y, b = blockIdx.z;
    f32x4 acc[2][2]; zero_acc(acc);
    mfma_core64(o2b + ((long)b * 256 + mt * 64) * 512, 512,
                TyTb + (long)qt * 64 * 512, 512, 16, acc);
    const int t = threadIdx.x, lane = t & 63, w = t >> 6;
    const int wr = w >> 1, wc = w & 1, fr = lane & 15, kg = lane >> 4;
    #pragma unroll
    for (int mi = 0; mi < 2; mi++)
    #pragma unroll
    for (int ni = 0; ni < 2; ni++)
    #pragma unroll
    for (int j = 0; j < 4; j++) {
        const int n = mt * 64 + wr * 32 + mi * 16 + kg * 4 + j;
        const int q = qt * 64 + wc * 32 + ni * 16 + fr;
        out[((long)b * 256 + n) * 512 + q] = acc[mi][ni][j];
    }
}

// ---------------------------------------------------------------------------
extern "C" void kernel_launch(void* const* d_in, const int* in_sizes, int n_in,
                              void* d_out, int out_size, void* d_ws, size_t ws_size,
                              hipStream_t stream)
{
    const float* z       = (const float*)d_in[0];
    const float* y_q     = (const float*)d_in[1];
    const float* x_k     = (const float*)d_in[2];
    const float* Theta_x = (const float*)d_in[3];
    const float* Theta_y = (const float*)d_in[4];
    const float* Lam_x   = (const float*)d_in[5];
    const float* Lam_y   = (const float*)d_in[6];
    const float* Lam_zx  = (const float*)d_in[7];
    const float* Lam_zy  = (const float*)d_in[8];
    float* out = (float*)d_out;

    // --- workspace (ushort offsets, all disjoint, ~13.9 MiB total) ---
    ushort_t* U = (ushort_t*)d_ws;
    ushort_t* xkb  = U;               // 262144  [b][m][512]
    ushort_t* yqb  = U + 262144;      // 262144  [b][n][512]
    ushort_t* WxTb = U + 524288;      // 524288  [k][128dc][512p]
    ushort_t* WyTb = U + 1048576;     // 262144  [k][64d][512p]
    ushort_t* Zyb  = U + 1310720;     // 65536   [k][128r][64d]
    ushort_t* Zxb  = U + 1376256;     // 65536
    ushort_t* TyTb = U + 1441792;     // 262144  [q][k*64+d]
    ushort_t* xtb  = U + 1703936;     // 262144  [bk][m][64]
    ushort_t* ytb  = U + 1966080;     // 262144  [bk][n][64]
    ushort_t* xvTb = U + 2228224;     // 262144  [bk][64d][256m]
    ushort_t* wzyb = U + 2490368;     // 524288  [b][m][8k][128r]
    ushort_t* wzxb = U + 3014656;     // 524288  [b][n][8k][128r]
    ushort_t* Et   = U + 3538944;     // 1048576 [bk][n][256m]
    ushort_t* o2b  = U + 4587520;     // 262144  [b][n][512kd]
    float*    ssum = (float*)(U + 4849664);  // 4096 fp32 [bk][n]
    float*    t1   = (float*)(U + 4857856);  // 1048576 fp32 [bk][n][m] (4MB)

    convert_kernel<<<6672, 256, 0, stream>>>(x_k, y_q, Lam_x, Theta_x, Lam_y,
        Lam_zy, Lam_zx, Theta_y, xkb, yqb, WxTb, WyTb, Zyb, Zxb, TyTb, ssum);

    proj_kernel<<<dim3(16, 8, 2), 256, 0, stream>>>(xkb, yqb, WxTb, WyTb,
        xtb, ytb, xvTb);

    step2_kernel<<<512, 256, 0, stream>>>(xtb, ytb, Zyb, Zxb, wzyb, wzxb, t1);

    fused_score<<<dim3(16, 32, 2), 256, 0, stream>>>(z, wzyb, wzxb, t1,
        Et, ssum);

    ogemm_kernel<<<dim3(4, 16), 256, 0, stream>>>(Et, xvTb, ssum, o2b);

    ygemm_kernel<<<dim3(8, 4, 2), 256, 0, stream>>>(o2b, TyTb, out);
}

// Round 9
// 58.935 us; speedup vs baseline: 1.1921x; 1.1921x over previous
//
#include <hip/hip_runtime.h>
#include <hip/hip_bf16.h>

// B=2, M=256, N=256, K=8, P=Q=Pp=Qp=512, D=Dp=64, R=128, TEMP=8
#define LOG2E_OVER_T 0.18033688011112042f  // log2(e)/8

typedef __attribute__((ext_vector_type(8))) short short8;
typedef __attribute__((ext_vector_type(4))) float f32x4;
typedef unsigned short ushort_t;
typedef unsigned long long ull_t;

#define MFMA16(a, b, c) __builtin_amdgcn_mfma_f32_16x16x32_bf16(a, b, c, 0, 0, 0)

__device__ __forceinline__ ushort_t f2bf(float f) {
    union { float f; unsigned u; } v; v.f = f;
    unsigned r = (v.u + 0x7fffu + ((v.u >> 16) & 1u)) >> 16;
    return (ushort_t)r;
}

// async global->LDS, 16B per lane; LDS dest = wave-uniform base + lane*16
__device__ __forceinline__ void gload16(const float* g, float* l) {
    __builtin_amdgcn_global_load_lds(
        (const __attribute__((address_space(1))) void*)g,
        (__attribute__((address_space(3))) void*)l, 16, 0, 0);
}

// split 8 fp32 -> bf16 hi (truncate) + bf16 lo (residual, truncate).
__device__ __forceinline__ void split8(const float4 a, const float4 b,
                                       short8& hi, short8& lo)
{
    union { float f[8]; unsigned u[8]; } Z;
    Z.f[0] = a.x; Z.f[1] = a.y; Z.f[2] = a.z; Z.f[3] = a.w;
    Z.f[4] = b.x; Z.f[5] = b.y; Z.f[6] = b.z; Z.f[7] = b.w;
    union { unsigned u[4]; short8 s; } H, L;
    #pragma unroll
    for (int i = 0; i < 4; i++) {
        const unsigned u0 = Z.u[2 * i], u1 = Z.u[2 * i + 1];
        H.u[i] = __builtin_amdgcn_perm(u1, u0, 0x07060302u);  // [u0.hi16, u1.hi16]
        union { unsigned u; float f; } h0, h1;
        h0.u = u0 & 0xffff0000u; h1.u = u1 & 0xffff0000u;
        union { float f; unsigned u; } l0, l1;
        l0.f = Z.f[2 * i] - h0.f; l1.f = Z.f[2 * i + 1] - h1.f;
        L.u[i] = __builtin_amdgcn_perm(l1.u, l0.u, 0x07060302u);
    }
    hi = H.s; lo = L.s;
}

// ---------------------------------------------------------------------------
// MFMA core: C[64x64] = A[64xK] * Bt[64xK]^T, bf16 in, fp32 acc. (4 waves)
// ---------------------------------------------------------------------------
__device__ __forceinline__ void mfma_core64(
    const ushort_t* __restrict__ Ag, int lda,
    const ushort_t* __restrict__ Btg, int ldb,
    int ksteps, f32x4 acc[2][2])
{
    __shared__ __align__(16) ushort_t As[64 * 40];
    __shared__ __align__(16) ushort_t Bs[64 * 40];
    const int t = threadIdx.x;
    const int srow = t >> 2, skc = (t & 3) * 8;
    const int lane = t & 63, w = t >> 6;
    const int wr = w >> 1, wc = w & 1;
    const int fr = lane & 15, kg = lane >> 4;
    const int aoff = (wr * 32 + fr) * 40 + kg * 8;
    const int boff = (wc * 32 + fr) * 40 + kg * 8;
    const long arow = (long)srow * lda + skc;
    const long brow = (long)srow * ldb + skc;

    short8 ra = *(const short8*)(Ag + arow);
    short8 rb = *(const short8*)(Btg + brow);
    for (int kt = 0; kt < ksteps; kt++) {
        __syncthreads();
        *(short8*)&As[srow * 40 + skc] = ra;
        *(short8*)&Bs[srow * 40 + skc] = rb;
        __syncthreads();
        if (kt + 1 < ksteps) {
            ra = *(const short8*)(Ag + arow + (kt + 1) * 32);
            rb = *(const short8*)(Btg + brow + (kt + 1) * 32);
        }
        short8 a0 = *(const short8*)&As[aoff];
        short8 a1 = *(const short8*)&As[aoff + 16 * 40];
        short8 b0 = *(const short8*)&Bs[boff];
        short8 b1 = *(const short8*)&Bs[boff + 16 * 40];
        acc[0][0] = MFMA16(a0, b0, acc[0][0]);
        acc[0][1] = MFMA16(a0, b1, acc[0][1]);
        acc[1][0] = MFMA16(a1, b0, acc[1][0]);
        acc[1][1] = MFMA16(a1, b1, acc[1][1]);
    }
}

__device__ __forceinline__ void zero_acc(f32x4 acc[2][2]) {
    const f32x4 z4 = {0.f, 0.f, 0.f, 0.f};
    acc[0][0] = z4; acc[0][1] = z4; acc[1][0] = z4; acc[1][1] = z4;
}

// ---------------------------------------------------------------------------
// convert: fp32 -> bf16 casts + layout permutes; also zeroes ssum.
// ---------------------------------------------------------------------------
__global__ __launch_bounds__(256)
void convert_kernel(const float* __restrict__ x_k, const float* __restrict__ y_q,
                    const float* __restrict__ Lam_x, const float* __restrict__ Theta_x,
                    const float* __restrict__ Lam_y, const float* __restrict__ Lam_zy,
                    const float* __restrict__ Lam_zx, const float* __restrict__ Theta_y,
                    ushort_t* __restrict__ xkb, ushort_t* __restrict__ yqb,
                    ushort_t* __restrict__ WxTb, ushort_t* __restrict__ WyTb,
                    ushort_t* __restrict__ Zyb, ushort_t* __restrict__ Zxb,
                    ushort_t* __restrict__ TyTb, float* __restrict__ ssum)
{
    int i = blockIdx.x * 256 + threadIdx.x;
    if (i < 262144) { xkb[i] = f2bf(x_k[i]); return; }
    i -= 262144;
    if (i < 262144) { yqb[i] = f2bf(y_q[i]); return; }
    i -= 262144;
    if (i < 524288) {  // WxTb[k][dc][p] = (dc<64 ? Lam_x : Theta_x)[k][p][dc%64]
        const int k = i >> 16, rem = i & 65535, dc = rem >> 9, p = i & 511;
        const float v = (dc < 64) ? Lam_x[((long)k * 512 + p) * 64 + dc]
                                  : Theta_x[((long)k * 512 + p) * 64 + dc - 64];
        WxTb[i] = f2bf(v); return;
    }
    i -= 524288;
    if (i < 262144) {  // WyTb[k][d][p] = Lam_y[k][p][d]
        const int k = i >> 15, d = (i >> 9) & 63, p = i & 511;
        WyTb[i] = f2bf(Lam_y[((long)k * 512 + p) * 64 + d]); return;
    }
    i -= 262144;
    if (i < 65536) { Zyb[i] = f2bf(Lam_zy[i]); return; }
    i -= 65536;
    if (i < 65536) { Zxb[i] = f2bf(Lam_zx[i]); return; }
    i -= 65536;
    if (i < 262144) {  // TyTb[q][k*64+d] = Theta_y[k][q][d]
        const int q = i >> 9, kd = i & 511, k = kd >> 6, d = kd & 63;
        TyTb[i] = f2bf(Theta_y[((long)k * 512 + q) * 64 + d]); return;
    }
    i -= 262144;
    ssum[i] = 0.f;  // 4096 entries
}

// ---------------------------------------------------------------------------
// proj: side0: [b,m] x WxT -> xtb (bf16 [bk][m][64]) + xvT (bf16 [bk][64][m])
//       side1: [b,n] x WyT -> ytb (bf16 [bk][n][64])
// ---------------------------------------------------------------------------
__global__ __launch_bounds__(256)
void proj_kernel(const ushort_t* __restrict__ xkb, const ushort_t* __restrict__ yqb,
                 const ushort_t* __restrict__ WxTb, const ushort_t* __restrict__ WyTb,
                 ushort_t* __restrict__ xtb, ushort_t* __restrict__ ytb,
                 ushort_t* __restrict__ xvTb)
{
    const int side = blockIdx.z;
    const int bx = blockIdx.x, by = blockIdx.y;
    if (side == 1 && bx >= 8) return;
    f32x4 acc[2][2]; zero_acc(acc);
    const int t = threadIdx.x, lane = t & 63, w = t >> 6;
    const int wr = w >> 1, wc = w & 1, fr = lane & 15, kg = lane >> 4;

    if (side == 0) {
        mfma_core64(xkb + (long)(by * 64) * 512, 512,
                    WxTb + (long)(bx * 64) * 512, 512, 16, acc);
        const int k = bx >> 1, isxv = bx & 1;
        #pragma unroll
        for (int mi = 0; mi < 2; mi++)
        #pragma unroll
        for (int ni = 0; ni < 2; ni++) {
            const int grow0 = by * 64 + wr * 32 + mi * 16 + kg * 4;
            const int b = grow0 >> 8, m0 = grow0 & 255;
            const int d = wc * 32 + ni * 16 + fr;
            if (!isxv) {
                #pragma unroll
                for (int j = 0; j < 4; j++)
                    xtb[(((long)(b * 8 + k)) * 256 + m0 + j) * 64 + d] = f2bf(acc[mi][ni][j]);
            } else {
                ull_t pk = (ull_t)f2bf(acc[mi][ni][0])
                         | ((ull_t)f2bf(acc[mi][ni][1]) << 16)
                         | ((ull_t)f2bf(acc[mi][ni][2]) << 32)
                         | ((ull_t)f2bf(acc[mi][ni][3]) << 48);
                *(ull_t*)&xvTb[(((long)(b * 8 + k)) * 64 + d) * 256 + m0] = pk;
            }
        }
    } else {
        mfma_core64(yqb + (long)(by * 64) * 512, 512,
                    WyTb + (long)(bx * 64) * 512, 512, 16, acc);
        const int k = bx;
        #pragma unroll
        for (int mi = 0; mi < 2; mi++)
        #pragma unroll
        for (int ni = 0; ni < 2; ni++)
        #pragma unroll
        for (int j = 0; j < 4; j++) {
            const int grow = by * 64 + wr * 32 + mi * 16 + kg * 4 + j;
            const int b = grow >> 8, n = grow & 255;
            const int d = wc * 32 + ni * 16 + fr;
            ytb[(((long)(b * 8 + k)) * 256 + n) * 64 + d] = f2bf(acc[mi][ni][j]);
        }
    }
}

// ---------------------------------------------------------------------------
// step2: bz<256:  wzyb[b][m][k][128] = bf16(xt @ Lam_zy^T), wzxb likewise.
//        bz>=256: t1[bk][n][m] = fp32(yt @ xt^T)  (xt.yt scores, transposed)
// ---------------------------------------------------------------------------
__global__ __launch_bounds__(256)
void step2_kernel(const ushort_t* __restrict__ xtb, const ushort_t* __restrict__ ytb,
                  const ushort_t* __restrict__ Zyb, const ushort_t* __restrict__ Zxb,
                  ushort_t* __restrict__ wzyb, ushort_t* __restrict__ wzxb,
                  float* __restrict__ t1)
{
    const int bz = blockIdx.x;  // 512
    const int t = threadIdx.x, lane = t & 63, w = t >> 6;
    const int wr = w >> 1, wc = w & 1, fr = lane & 15, kg = lane >> 4;

    if (bz < 256) {
        const int which = bz >> 7, idx = bz & 127;
        const int bk = idx >> 3, tile = idx & 7, mt = tile >> 1, nt = tile & 1;
        const int k = bk & 7, b = bk >> 3;
        const ushort_t* Ag  = (which ? ytb : xtb) + ((long)bk * 256 + mt * 64) * 64;
        const ushort_t* Btg = (which ? Zxb : Zyb) + ((long)k * 128 + nt * 64) * 64;
        ushort_t* C = which ? wzxb : wzyb;
        f32x4 acc[2][2]; zero_acc(acc);
        mfma_core64(Ag, 64, Btg, 64, 2, acc);
        #pragma unroll
        for (int mi = 0; mi < 2; mi++)
        #pragma unroll
        for (int ni = 0; ni < 2; ni++)
        #pragma unroll
        for (int j = 0; j < 4; j++) {
            const int m_glob = mt * 64 + wr * 32 + mi * 16 + kg * 4 + j;
            const int r_glob = nt * 64 + wc * 32 + ni * 16 + fr;
            C[(((long)b * 256 + m_glob) * 8 + k) * 128 + r_glob] = f2bf(acc[mi][ni][j]);
        }
    } else {
        const int idx = bz - 256;
        const int bk = idx >> 4, tile = idx & 15, nt2 = tile >> 2, mt2 = tile & 3;
        f32x4 acc[2][2]; zero_acc(acc);
        mfma_core64(ytb + ((long)bk * 256 + nt2 * 64) * 64, 64,
                    xtb + ((long)bk * 256 + mt2 * 64) * 64, 64, 2, acc);
        #pragma unroll
        for (int mi = 0; mi < 2; mi++)
        #pragma unroll
        for (int ni = 0; ni < 2; ni++)
        #pragma unroll
        for (int j = 0; j < 4; j++) {
            const int n_glob = nt2 * 64 + wr * 32 + mi * 16 + kg * 4 + j;
            const int m_glob = mt2 * 64 + wc * 32 + ni * 16 + fr;
            t1[((long)bk * 256 + n_glob) * 256 + m_glob] = acc[mi][ni][j];
        }
    }
}

// ---------------------------------------------------------------------------
// fused_score v6: block = 8m x 16n tile, 4 r-quarter waves.
// z staged per 8n chunk (32KB) via global_load_lds with PRE-SWIZZLED global
// source (16B slot key = (m^n)&7) -> linear LDS dest, conflict-free b128
// reads for both p2 (rows=n) and p3 (rows=m). DMA queue supplies MLP; wave
// overlap across 3 blocks/CU pipelines the chunks (m97 pattern).
// ---------------------------------------------------------------------------
__global__ __launch_bounds__(256)
void fused_score(const float* __restrict__ z,
                 const ushort_t* __restrict__ wzyb, const ushort_t* __restrict__ wzxb,
                 const float* __restrict__ t1, ushort_t* __restrict__ Et,
                 float* __restrict__ ssum)
{
    const int nt = blockIdx.x, mt = blockIdx.y, b = blockIdx.z;
    const int nbase = nt * 16, m0 = mt * 8;
    __shared__ __align__(16) float zs[8192];      // 32KB [row=m*8+nl][32 slots]
    __shared__ float sc[4][8][8][17];             // 17.4KB

    const int tid = threadIdx.x;
    const int lane = tid & 63, w = tid >> 6;       // w = r-quarter
    const int fr = lane & 15, kg = lane >> 4;
    const int f8 = fr & 7;

    // per-lane staging geometry (same for both chunks; only n0c changes)
    const int js   = w * 512 + lane;               // base 16B index; +64 per issue
    for (int c = 0; c < 2; c++) {
        const int n0c = nbase + c * 8;

        // ---- stage chunk c: 8 issues/wave, pre-swizzled source
        #pragma unroll
        for (int i = 0; i < 8; i++) {
            const int j   = js + i * 64;
            const int row = j >> 5;                 // m*8 + nl
            const int m_l = row >> 3, n_l = row & 7;
            const int sl  = (j & 31) ^ ((m_l ^ n_l) & 7);
            const float* src = z + (((long)b * 256 + m0 + m_l) * 256 + n0c + n_l) * 128 + sl * 4;
            gload16(src, &zs[(w * 8 + i) * 256]);
        }
        __syncthreads();   // drains vmcnt; chunk visible

        // ---- p2: termB. per m: A rows = n (8 valid, dup), B = wzy[m][k][r-q]
        #pragma unroll
        for (int m = 0; m < 8; m++) {
            const int row = m * 8 + f8;
            const int key = (m ^ f8) & 7;
            const int s0 = (w * 8 + kg * 2) ^ key, s1 = (w * 8 + kg * 2 + 1) ^ key;
            const float4 za = *(const float4*)&zs[row * 128 + s0 * 4];
            const float4 zb = *(const float4*)&zs[row * 128 + s1 * 4];
            const short8 wv = *(const short8*)(wzyb
                + (((long)b * 256 + m0 + m) * 8 + f8) * 128 + w * 32 + kg * 8);
            short8 hi, lo;
            split8(za, zb, hi, lo);
            f32x4 acc = {0.f, 0.f, 0.f, 0.f};
            acc = MFMA16(hi, wv, acc);
            acc = MFMA16(lo, wv, acc);
            // D[row=kg*4+j -> n=(row&7), col=fr -> k]; rows 0..7 valid
            if (fr < 8 && kg < 2) {
                #pragma unroll
                for (int j = 0; j < 4; j++)
                    sc[w][m][fr][c * 8 + kg * 4 + j] = acc[j];
            }
        }

        // ---- p3: termC. per n: A rows = m (8 valid, dup), B = wzx[n][k][r-q]
        #pragma unroll
        for (int nl = 0; nl < 8; nl++) {
            const int row = f8 * 8 + nl;
            const int key = (f8 ^ nl) & 7;
            const int s0 = (w * 8 + kg * 2) ^ key, s1 = (w * 8 + kg * 2 + 1) ^ key;
            const float4 za = *(const float4*)&zs[row * 128 + s0 * 4];
            const float4 zb = *(const float4*)&zs[row * 128 + s1 * 4];
            const short8 wv = *(const short8*)(wzxb
                + (((long)b * 256 + n0c + nl) * 8 + f8) * 128 + w * 32 + kg * 8);
            short8 hi, lo;
            split8(za, zb, hi, lo);
            f32x4 acc = {0.f, 0.f, 0.f, 0.f};
            acc = MFMA16(hi, wv, acc);
            acc = MFMA16(lo, wv, acc);
            // D[row=kg*4+j -> m=(row&7), col=fr -> k]; rows 0..7 valid
            if (fr < 8 && kg < 2) {
                #pragma unroll
                for (int j = 0; j < 4; j++)
                    sc[w][kg * 4 + j][fr][c * 8 + nl] += acc[j];
            }
        }
        __syncthreads();   // compute(c) done before restaging zs
    }

    // ---- epilogue: 128 threads, one (k,n) each: sum quarters + t1, exp
    if (tid < 128) {
        const int k = tid >> 4, n = tid & 15;
        const float* tp = t1 + (((long)b * 8 + k) * 256 + nbase + n) * 256 + m0;
        const float4 t0 = *(const float4*)(tp);
        const float4 t4 = *(const float4*)(tp + 4);
        const float tv[8] = {t0.x, t0.y, t0.z, t0.w, t4.x, t4.y, t4.z, t4.w};
        float s8 = 0.f;
        ushort_t eb[8];
        #pragma unroll
        for (int m = 0; m < 8; m++) {
            const float s = sc[0][m][k][n] + sc[1][m][k][n]
                          + sc[2][m][k][n] + sc[3][m][k][n] + tv[m];
            const float e = exp2f(s * LOG2E_OVER_T);
            eb[m] = f2bf(e);
            s8 += e;
        }
        *(short8*)(Et + (((long)b * 8 + k) * 256 + nbase + n) * 256 + m0) = *(short8*)eb;
        atomicAdd(&ssum[(b * 8 + k) * 256 + nbase + n], s8);
    }
}

// ---------------------------------------------------------------------------
// ogemm: o2b[b][n][k*64+d] = bf16( (1/ssum[bk][n]) * sum_m Et[bk][n][m]*xvT[bk][d][m] )
// ---------------------------------------------------------------------------
__global__ __launch_bounds__(256)
void ogemm_kernel(const ushort_t* __restrict__ Et, const ushort_t* __restrict__ xvTb,
                  const float* __restrict__ ssum, ushort_t* __restrict__ o2b)
{
    const int mt = blockIdx.x, bk = blockIdx.y;
    f32x4 acc[2][2]; zero_acc(acc);
    mfma_core64(Et + ((long)bk * 256 + mt * 64) * 256, 256,
                xvTb + (long)bk * 64 * 256, 256, 8, acc);
    const int t = threadIdx.x, lane = t & 63, w = t >> 6;
    const int wr = w >> 1, wc = w & 1, fr = lane & 15, kg = lane >> 4;
    const int b = bk >> 3, k = bk & 7;
    #pragma unroll
    for (int mi = 0; mi < 2; mi++)
    #pragma unroll
    for (int j = 0; j < 4; j++) {
        const int n = mt * 64 + wr * 32 + mi * 16 + kg * 4 + j;
        const float inv = 1.0f / ssum[bk * 256 + n];
        #pragma unroll
        for (int ni = 0; ni < 2; ni++) {
            const int d = wc * 32 + ni * 16 + fr;
            o2b[((long)b * 256 + n) * 512 + k * 64 + d] = f2bf(acc[mi][ni][j] * inv);
        }
    }
}

// ---------------------------------------------------------------------------
// ygemm: out[b][n][q] = sum_kd o2b[b][n][kd] * TyTb[q][kd]   (fp32 out)
// ---------------------------------------------------------------------------
__global__ __launch_bounds__(256)
void ygemm_kernel(const ushort_t* __restrict__ o2b, const ushort_t* __restrict__ TyTb,
                  float* __restrict__ out)
{
    const int qt = blockIdx.x, mt = blockIdx.y, b = blockIdx.z;
    f32x4 acc[2][2]; zero_acc(acc);
    mfma_core64(o2b + ((long)b * 256 + mt * 64) * 512, 512,
                TyTb + (long)qt * 64 * 512, 512, 16, acc);
    const int t = threadIdx.x, lane = t & 63, w = t >> 6;
    const int wr = w >> 1, wc = w & 1, fr = lane & 15, kg = lane >> 4;
    #pragma unroll
    for (int mi = 0; mi < 2; mi++)
    #pragma unroll
    for (int ni = 0; ni < 2; ni++)
    #pragma unroll
    for (int j = 0; j < 4; j++) {
        const int n = mt * 64 + wr * 32 + mi * 16 + kg * 4 + j;
        const int q = qt * 64 + wc * 32 + ni * 16 + fr;
        out[((long)b * 256 + n) * 512 + q] = acc[mi][ni][j];
    }
}

// ---------------------------------------------------------------------------
extern "C" void kernel_launch(void* const* d_in, const int* in_sizes, int n_in,
                              void* d_out, int out_size, void* d_ws, size_t ws_size,
                              hipStream_t stream)
{
    const float* z       = (const float*)d_in[0];
    const float* y_q     = (const float*)d_in[1];
    const float* x_k     = (const float*)d_in[2];
    const float* Theta_x = (const float*)d_in[3];
    const float* Theta_y = (const float*)d_in[4];
    const float* Lam_x   = (const float*)d_in[5];
    const float* Lam_y   = (const float*)d_in[6];
    const float* Lam_zx  = (const float*)d_in[7];
    const float* Lam_zy  = (const float*)d_in[8];
    float* out = (float*)d_out;

    // --- workspace (ushort offsets, all disjoint, ~13.9 MiB total) ---
    ushort_t* U = (ushort_t*)d_ws;
    ushort_t* xkb  = U;               // 262144  [b][m][512]
    ushort_t* yqb  = U + 262144;      // 262144  [b][n][512]
    ushort_t* WxTb = U + 524288;      // 524288  [k][128dc][512p]
    ushort_t* WyTb = U + 1048576;     // 262144  [k][64d][512p]
    ushort_t* Zyb  = U + 1310720;     // 65536   [k][128r][64d]
    ushort_t* Zxb  = U + 1376256;     // 65536
    ushort_t* TyTb = U + 1441792;     // 262144  [q][k*64+d]
    ushort_t* xtb  = U + 1703936;     // 262144  [bk][m][64]
    ushort_t* ytb  = U + 1966080;     // 262144  [bk][n][64]
    ushort_t* xvTb = U + 2228224;     // 262144  [bk][64d][256m]
    ushort_t* wzyb = U + 2490368;     // 524288  [b][m][8k][128r]
    ushort_t* wzxb = U + 3014656;     // 524288  [b][n][8k][128r]
    ushort_t* Et   = U + 3538944;     // 1048576 [bk][n][256m]
    ushort_t* o2b  = U + 4587520;     // 262144  [b][n][512kd]
    float*    ssum = (float*)(U + 4849664);  // 4096 fp32 [bk][n]
    float*    t1   = (float*)(U + 4857856);  // 1048576 fp32 [bk][n][m] (4MB)

    convert_kernel<<<6672, 256, 0, stream>>>(x_k, y_q, Lam_x, Theta_x, Lam_y,
        Lam_zy, Lam_zx, Theta_y, xkb, yqb, WxTb, WyTb, Zyb, Zxb, TyTb, ssum);

    proj_kernel<<<dim3(16, 8, 2), 256, 0, stream>>>(xkb, yqb, WxTb, WyTb,
        xtb, ytb, xvTb);

    step2_kernel<<<512, 256, 0, stream>>>(xtb, ytb, Zyb, Zxb, wzyb, wzxb, t1);

    fused_score<<<dim3(16, 32, 2), 256, 0, stream>>>(z, wzyb, wzxb, t1,
        Et, ssum);

    ogemm_kernel<<<dim3(4, 16), 256, 0, stream>>>(Et, xvTb, ssum, o2b);

    ygemm_kernel<<<dim3(8, 4, 2), 256, 0, stream>>>(o2b, TyTb, out);
}